// Round 12
// baseline (4279.421 us; speedup 1.0000x reference)
//
#include <hip/hip_runtime.h>

typedef unsigned short u16;
typedef unsigned int   u32;
typedef unsigned long long u64;
typedef __attribute__((ext_vector_type(8))) short short8v;
typedef __attribute__((ext_vector_type(4))) float f32x4;
typedef __attribute__((ext_vector_type(4))) unsigned int u32x4;

#define DINL __device__ __forceinline__

DINL u16 f2bf(float f){ union{float f;u32 u;} v{f}; return (u16)((v.u + 0x7fffu + ((v.u>>16)&1u))>>16); }
DINL float bf2f(u16 b){ union{u32 u;float f;} v{(u32)b<<16}; return v.f; }
DINL f32x4 MFMA16(short8v a, short8v b, f32x4 c){ return __builtin_amdgcn_mfma_f32_16x16x32_bf16(a,b,c,0,0,0); }
DINL void gl16(const void* g, void* l){
  __builtin_amdgcn_global_load_lds((const __attribute__((address_space(1))) void*)g,
                                   (__attribute__((address_space(3))) void*)l, 16, 0, 0);
}
DINL float wredd(float v){
#pragma unroll
  for (int m=1;m<64;m<<=1) v += __shfl_xor(v, m);
  return v;
}
DINL float sigm(float x){ return 1.f/(1.f+__expf(-x)); }
DINL float tanh_(float x){ return 2.f/(1.f+__expf(-2.f*x)) - 1.f; }

// ---------------- zero fill (16B per thread, exact grid) ----------------
__global__ __launch_bounds__(256) void zerok(u32* __restrict__ dst){
  size_t i = ((size_t)blockIdx.x*256 + threadIdx.x)*4;
  u32x4 z = {0,0,0,0};
  *(u32x4*)(dst + i) = z;
}

// ---------------- generic fp32 -> bf16 convert ----------------
__global__ __launch_bounds__(256) void cvtk(const float* __restrict__ src, u16* __restrict__ dst, int n){
  int i = (blockIdx.x*256 + threadIdx.x)*4;
  float4 v = *(const float4*)(src + i);
  dst[i+0]=f2bf(v.x); dst[i+1]=f2bf(v.y); dst[i+2]=f2bf(v.z); dst[i+3]=f2bf(v.w);
}

// ---------------- 128x128 bf16 MFMA GEMM, m97 structure ----------------
template<int EPI>
__global__ __launch_bounds__(256) void gemm128(
    const u16* __restrict__ A, const u16* __restrict__ W,
    const float* __restrict__ bias0, const float* __restrict__ bias1, const float* __restrict__ bias2,
    const u16* __restrict__ resid, u16* __restrict__ out, int M, int N, int K)
{
  __shared__ __align__(16) u16 Al[128*64];
  __shared__ __align__(16) u16 Bl[128*64];
  const int tid = threadIdx.x, lane = tid & 63, w = tid >> 6;
  const int wr = w >> 1, wc = w & 1;
  const int m0 = blockIdx.y * 128, n0 = blockIdx.x * 128;
  f32x4 acc[4][4] = {};
  for (int k0 = 0; k0 < K; k0 += 64) {
#pragma unroll
    for (int j = 0; j < 4; ++j) {
      int idx = (j*4 + w)*64 + lane;
      int r = idx >> 3, c8 = idx & 7;
      gl16(A + (size_t)(m0 + r)*K + k0 + c8*8, (void*)(Al + (size_t)(j*4+w)*512));
      gl16(W + (size_t)(n0 + r)*K + k0 + c8*8, (void*)(Bl + (size_t)(j*4+w)*512));
    }
    __syncthreads();
#pragma unroll
    for (int kk = 0; kk < 2; ++kk) {
      short8v af[4], bf[4];
#pragma unroll
      for (int i = 0; i < 4; ++i)
        af[i] = *(const short8v*)(Al + ((wr*64 + i*16 + (lane&15))*64 + kk*32 + (lane>>4)*8));
#pragma unroll
      for (int i = 0; i < 4; ++i)
        bf[i] = *(const short8v*)(Bl + ((wc*64 + i*16 + (lane&15))*64 + kk*32 + (lane>>4)*8));
#pragma unroll
      for (int mi=0;mi<4;++mi)
#pragma unroll
        for (int ni=0;ni<4;++ni)
          acc[mi][ni] = MFMA16(af[mi], bf[ni], acc[mi][ni]);
    }
    __syncthreads();
  }
#pragma unroll
  for (int mi=0;mi<4;++mi)
#pragma unroll
    for (int ni=0;ni<4;++ni)
#pragma unroll
      for (int r=0;r<4;++r) {
        int m = m0 + wr*64 + mi*16 + (lane>>4)*4 + r;
        int n = n0 + wc*64 + ni*16 + (lane&15);
        float v = acc[mi][ni][r];
        if constexpr (EPI == 0) {
          int t = m & 1023;
          float ang = (float)t * expf((float)(n & ~1) * (-9.210340371976184f/512.f));
          v += bias0[n] + ((n & 1) ? cosf(ang) : sinf(ang));
          out[(size_t)m*512 + n] = f2bf(v);
        } else if constexpr (EPI == 1) {
          int g = n >> 9, n5 = n & 511, hh = n5 >> 6, dh = n5 & 63;
          v += (g==0 ? bias0 : g==1 ? bias1 : bias2)[n5];
          size_t bh = (size_t)((m>>10)*8 + hh);
          u16 val = f2bf(v);
          if (g == 0)      out[(bh*1024 + (m&1023))*64 + dh] = val;
          else if (g == 1) out[4194304 + (bh*1024 + (m&1023))*64 + dh] = val;
          else             out[8388608 + (bh*64 + dh)*1024 + (m&1023)] = val;
        } else {
          v += bias0[n] + bf2f(resid[(size_t)m*512 + n]);
          out[(size_t)m*512 + n] = f2bf(v);
        }
      }
}

// ---------------- causal flash attention ----------------
__global__ __launch_bounds__(256) void attnk(const u16* __restrict__ qb, const u16* __restrict__ kb,
                                             const u16* __restrict__ vt, u16* __restrict__ attno)
{
  __shared__ __align__(16) u16 P[4][16][72];
  const int tid = threadIdx.x, lane = tid & 63, w = tid >> 6;
  const int bh = blockIdx.x >> 4, qblk = blockIdx.x & 15;
  const int b = bh >> 3, h = bh & 7;
  const float scale = 0.125f;
  short8v qf[2];
  {
    const u16* qbase = qb + ((size_t)bh*1024 + qblk*64 + w*16)*64;
#pragma unroll
    for (int kk=0;kk<2;++kk)
      qf[kk] = *(const short8v*)(qbase + (size_t)(lane&15)*64 + kk*32 + (lane>>4)*8);
  }
  f32x4 o[4] = {};
  float mrun[4], lrun[4];
#pragma unroll
  for (int r=0;r<4;++r){ mrun[r] = -1e30f; lrun[r] = 0.f; }
  for (int kblk = 0; kblk <= qblk; ++kblk) {
    f32x4 s[4] = {};
#pragma unroll
    for (int kk=0;kk<2;++kk)
#pragma unroll
      for (int nt=0;nt<4;++nt) {
        short8v kf = *(const short8v*)(kb + ((size_t)bh*1024 + kblk*64 + nt*16 + (lane&15))*64 + kk*32 + (lane>>4)*8);
        s[nt] = MFMA16(qf[kk], kf, s[nt]);
      }
    float pnew[4][4];
#pragma unroll
    for (int r=0;r<4;++r) {
      int q = qblk*64 + w*16 + (lane>>4)*4 + r;
      float sv[4]; float rowmax = -1e30f;
#pragma unroll
      for (int nt=0;nt<4;++nt) {
        int key = kblk*64 + nt*16 + (lane&15);
        float x = s[nt][r]*scale;
        if (key > q) x = -1e30f;
        sv[nt] = x; rowmax = fmaxf(rowmax, x);
      }
#pragma unroll
      for (int msk=1; msk<16; msk<<=1) rowmax = fmaxf(rowmax, __shfl_xor(rowmax, msk));
      float mnew = fmaxf(mrun[r], rowmax);
      float sf = __expf(mrun[r]-mnew);
      float psum = 0.f;
#pragma unroll
      for (int nt=0;nt<4;++nt){ float p = __expf(sv[nt]-mnew); pnew[nt][r]=p; psum += p; }
#pragma unroll
      for (int msk=1; msk<16; msk<<=1) psum += __shfl_xor(psum, msk);
      lrun[r] = lrun[r]*sf + psum;
      mrun[r] = mnew;
#pragma unroll
      for (int nt=0;nt<4;++nt) o[nt][r] *= sf;
    }
#pragma unroll
    for (int nt=0;nt<4;++nt)
#pragma unroll
      for (int r=0;r<4;++r)
        P[w][(lane>>4)*4+r][nt*16+(lane&15)] = f2bf(pnew[nt][r]);
#pragma unroll
    for (int kk=0;kk<2;++kk) {
      short8v pf = *(const short8v*)&P[w][lane&15][kk*32 + (lane>>4)*8];
#pragma unroll
      for (int nt=0;nt<4;++nt) {
        short8v vf = *(const short8v*)(vt + ((size_t)bh*64 + nt*16 + (lane&15))*1024 + kblk*64 + kk*32 + (lane>>4)*8);
        o[nt] = MFMA16(pf, vf, o[nt]);
      }
    }
  }
#pragma unroll
  for (int nt=0;nt<4;++nt)
#pragma unroll
    for (int r=0;r<4;++r) {
      int q = qblk*64 + w*16 + (lane>>4)*4 + r;
      int dh = nt*16 + (lane&15);
      attno[((size_t)b*1024 + q)*512 + h*64 + dh] = f2bf(o[nt][r] / lrun[r]);
    }
}

// ---------------- LayerNorm 1 (rows of 512), write x_lstm [t][b][512] bf16 ----------------
__global__ __launch_bounds__(256) void ln1k(const u16* __restrict__ pre, const float* __restrict__ g1,
                                            const float* __restrict__ b1, u16* __restrict__ xl){
  int row = blockIdx.x*4 + (threadIdx.x>>6), lane = threadIdx.x&63;
  short8v xv = *(const short8v*)(pre + (size_t)row*512 + lane*8);
  float v[8], s=0.f, s2=0.f;
#pragma unroll
  for (int e=0;e<8;++e){ v[e]=bf2f((u16)xv[e]); s+=v[e]; s2+=v[e]*v[e]; }
  s = wredd(s); s2 = wredd(s2);
  float mu = s*(1.f/512.f);
  float rs = rsqrtf(s2*(1.f/512.f) - mu*mu + 1e-5f);
  int b = row>>10, t = row&1023;
  short8v ov;
#pragma unroll
  for (int e=0;e<8;++e){ int c=lane*8+e; ov[e]=(short)f2bf((v[e]-mu)*rs*g1[c]+b1[c]); }
  *(short8v*)(xl + ((size_t)t*8 + b)*512 + lane*8) = ov;
}

// ---------------- persistent bidirectional LSTM — R6 protocol + pad-9 reduce ----------------
// 32 WGs x 512 thr: d = blk>>4, slice = blk&15 owns 32 units. Wave w owns K-eighth.
// Weights as MFMA B-fragments in VGPRs. Exchange: tagged u32 hot window (parity p=t&1),
// producer sc0 sc1 write-through; consumer batched 4x global_load_dwordx4 sc0 sc1 + ONE
// vmcnt(0) per retry (R6's proven single-round-trip poll).
// Reduce: LDS [par][8 nt][4 rg][32 lc][9] pad-9 layout -> bank-conflict-free (R7-proven).
__global__ __launch_bounds__(512) void lstmk(
    const u16* __restrict__ xl,
    const float* __restrict__ wih_f, const float* __restrict__ whh_f,
    const float* __restrict__ bih_f, const float* __restrict__ bhh_f,
    const float* __restrict__ wih_b, const float* __restrict__ whh_b,
    const float* __restrict__ bih_b, const float* __restrict__ bhh_b,
    u32* __restrict__ hx, u16* __restrict__ hs)
{
  extern __shared__ float RED[];        // [2][8 nt][4 rg][32 lc][9] = 73728 B

  const int tid = threadIdx.x, lane = tid&63, w = tid>>6;
  const int d = blockIdx.x >> 4, slice = blockIdx.x & 15, u0 = slice*32;
  const float* WIHg = d ? wih_b : wih_f;
  const float* WHHg = d ? whh_b : whh_f;
  const float* BIH  = d ? bih_b : bih_f;
  const float* BHH  = d ? bhh_b : bhh_f;

  const int l15 = lane&15, l16 = lane>>4;

  // ---- load weight fragments into registers: frag[nt][kk], nt = g*2+uh ----
  short8v wi[8][2], wh[8][2];
#pragma unroll
  for (int nt=0; nt<8; ++nt) {
    const int g = nt>>1, uh = nt&1;
    const size_t row = (size_t)(g*512 + u0 + uh*16 + l15);
#pragma unroll
    for (int kk=0; kk<2; ++kk) {
      const int k = w*64 + kk*32 + l16*8;
      const float* pi = WIHg + row*512 + k;
      const float* ph = WHHg + row*512 + k;
      float4 a0 = *(const float4*)pi, a1 = *(const float4*)(pi+4);
      float4 b0 = *(const float4*)ph, b1 = *(const float4*)(ph+4);
      short8v si, sh;
      si[0]=(short)f2bf(a0.x); si[1]=(short)f2bf(a0.y); si[2]=(short)f2bf(a0.z); si[3]=(short)f2bf(a0.w);
      si[4]=(short)f2bf(a1.x); si[5]=(short)f2bf(a1.y); si[6]=(short)f2bf(a1.z); si[7]=(short)f2bf(a1.w);
      sh[0]=(short)f2bf(b0.x); sh[1]=(short)f2bf(b0.y); sh[2]=(short)f2bf(b0.z); sh[3]=(short)f2bf(b0.w);
      sh[4]=(short)f2bf(b1.x); sh[5]=(short)f2bf(b1.y); sh[6]=(short)f2bf(b1.z); sh[7]=(short)f2bf(b1.w);
      wi[nt][kk] = si; wh[nt][kk] = sh;
    }
  }

  const bool act = tid < 256;
  const int b_ = tid>>5, u_ = tid&31;           // valid when act
  float c_state = 0.f, bias_c[4];
  if (act)
#pragma unroll
    for (int g=0;g<4;++g) bias_c[g] = BIH[g*512+u0+u_] + BHH[g*512+u0+u_];

  __syncthreads();

  for (int t = 0; t < 1024; ++t) {
    const int te = d ? 1023 - t : t;
    f32x4 acc[8] = {};
    { // x @ wih^T — h-independent
      const u16* xb = xl + ((size_t)te*8 + (lane&7))*512 + w*64 + l16*8;
      short8v xf0 = *(const short8v*)(xb);
      short8v xf1 = *(const short8v*)(xb + 32);
#pragma unroll
      for (int nt=0; nt<8; ++nt) acc[nt] = MFMA16(xf0, wi[nt][0], acc[nt]);
#pragma unroll
      for (int nt=0; nt<8; ++nt) acc[nt] = MFMA16(xf1, wi[nt][1], acc[nt]);
    }
    if (t > 0) {
      const u32 tg = (u32)t;
      // hot window parity (t-1)&1; this wave's K-eighth fragment
      const u32* pb = hx + ((size_t)d*2 + ((t-1)&1))*4096 + (size_t)(lane&7)*512 + w*64 + l16*8;
      u32x4 q0,q1,q2,q3;
      for (;;) {
        asm volatile(
          "global_load_dwordx4 %0, %4, off sc0 sc1\n\t"
          "global_load_dwordx4 %1, %4, off offset:16 sc0 sc1\n\t"
          "global_load_dwordx4 %2, %4, off offset:128 sc0 sc1\n\t"
          "global_load_dwordx4 %3, %4, off offset:144 sc0 sc1\n\t"
          "s_waitcnt vmcnt(0)"
          : "=&v"(q0),"=&v"(q1),"=&v"(q2),"=&v"(q3)
          : "v"(pb));
        bool ok = true;
#pragma unroll
        for (int e=0;e<4;++e) {
          ok = ok && ((q0[e]&0xffffu)==tg) && ((q1[e]&0xffffu)==tg)
                  && ((q2[e]&0xffffu)==tg) && ((q3[e]&0xffffu)==tg);
        }
        if (__all(ok)) break;
        __builtin_amdgcn_s_sleep(1);
      }
      short8v hf0, hf1;
#pragma unroll
      for (int e=0;e<4;++e) {
        hf0[e]   = (short)(q0[e] >> 16);
        hf0[4+e] = (short)(q1[e] >> 16);
        hf1[e]   = (short)(q2[e] >> 16);
        hf1[4+e] = (short)(q3[e] >> 16);
      }
#pragma unroll
      for (int nt=0; nt<8; ++nt) acc[nt] = MFMA16(hf0, wh[nt][0], acc[nt]);
#pragma unroll
      for (int nt=0; nt<8; ++nt) acc[nt] = MFMA16(hf1, wh[nt][1], acc[nt]);
    }
    // ---- conflict-free reduce: R[par][nt][rg][lc][9], scalar writes at stride 9 ----
    float* R = RED + (size_t)(t & 1)*9216;
    if (lane < 32)
#pragma unroll
      for (int nt=0; nt<8; ++nt)
#pragma unroll
        for (int rg=0; rg<4; ++rg)
          R[(((size_t)nt*4 + rg)*32 + lane)*9 + w] = acc[nt][rg];
    __syncthreads();
    if (act) {
      const int uh = u_>>4, lc = (u_&15) + 16*(b_>>2), rg = b_&3;
      float gates[4];
#pragma unroll
      for (int g=0;g<4;++g) {
        const float* q = R + (((size_t)(g*2+uh)*4 + rg)*32 + lc)*9;
        gates[g] = ((q[0]+q[1])+(q[2]+q[3])) + ((q[4]+q[5])+(q[6]+q[7])) + bias_c[g];
      }
      float ig = sigm(gates[0]), fg = sigm(gates[1]), gg = tanh_(gates[2]), og = sigm(gates[3]);
      c_state = fg*c_state + ig*gg;
      u16 hv = f2bf(og * tanh_(c_state));
      // history (plain cached store, consumed by ln2k after kernel end)
      hs[((size_t)(d*1024 + te)*8 + b_)*512 + u0 + u_] = hv;
      // hot-window tagged word (write-through to the device coherence point)
      u32 word = ((u32)hv << 16) | (u32)(t + 1);
      u32* dst = hx + ((size_t)d*2 + (t&1))*4096 + (size_t)b_*512 + u0 + u_;
      asm volatile("global_store_dword %0, %1, off sc0 sc1" :: "v"(dst), "v"(word) : "memory");
    }
    // no trailing barrier: RED double-buffered by t&1; readiness carried by tags
  }
}

// ---------------- LayerNorm 2 + time-mean accumulate ----------------
__global__ __launch_bounds__(256) void ln2k(const u16* __restrict__ hs, const float* __restrict__ g2,
                                            const float* __restrict__ b2, float* __restrict__ emb){
  __shared__ float accl[4][1024];
  int b = blockIdx.x>>4, chunk = blockIdx.x&15;
  int lane = threadIdx.x&63, w = threadIdx.x>>6;
  for (int i=lane;i<1024;i+=64) accl[w][i]=0.f;
#pragma unroll 1
  for (int i=0;i<16;++i) {
    int t = chunk*64 + w*16 + i;
    short8v xf = *(const short8v*)(hs + ((size_t)t*8 + b)*512 + lane*8);
    short8v xb = *(const short8v*)(hs + ((size_t)(1024+t)*8 + b)*512 + lane*8);
    float vf[8], vb[8], s=0.f, s2=0.f;
#pragma unroll
    for (int e=0;e<8;++e){ vf[e]=bf2f((u16)xf[e]); vb[e]=bf2f((u16)xb[e]);
                           s += vf[e]+vb[e]; s2 += vf[e]*vf[e]+vb[e]*vb[e]; }
    s = wredd(s); s2 = wredd(s2);
    float mu = s*(1.f/1024.f);
    float rs = rsqrtf(s2*(1.f/1024.f) - mu*mu + 1e-5f);
#pragma unroll
    for (int e=0;e<8;++e){
      int c = lane*8+e;
      accl[w][c]     += (vf[e]-mu)*rs*g2[c]     + b2[c];
      accl[w][512+c] += (vb[e]-mu)*rs*g2[512+c] + b2[512+c];
    }
  }
  __syncthreads();
  for (int c = threadIdx.x; c < 1024; c += 256)
    atomicAdd(emb + (size_t)b*1024 + c, accl[0][c]+accl[1][c]+accl[2][c]+accl[3][c]);
}

// ---------------- final projection ----------------
__global__ __launch_bounds__(256) void fink(const float* __restrict__ emb, const float* __restrict__ w_out,
                                            const float* __restrict__ b_out, float* __restrict__ out){
  int gid = blockIdx.x*256 + threadIdx.x;
  int n = gid>>3, b = gid&7;
  const float* e = emb + (size_t)b*1024;
  const float* wr = w_out + (size_t)n*1024;
  float s = 0.f;
  for (int k=0;k<1024;k+=4) {
    float4 ev = *(const float4*)(e+k);
    float4 wv = *(const float4*)(wr+k);
    s += ev.x*wv.x + ev.y*wv.y + ev.z*wv.z + ev.w*wv.w;
  }
  out[(size_t)b*512 + n] = b_out[n] + s*(1.f/1024.f);
}

// ---------------- workspace layout (bytes) ----------------
#define OFF_EMB   0u          // [8][1024] f32 = 32768           (zeroed each launch)
#define OFF_HX    32768u      // [2][2][8][512] u32 = 65536      (zeroed each launch)
#define OFF_A0    98304u      // [8192][256] bf16 = 4194304
#define OFF_WIN   4292608u    // [512][256] bf16 = 262144
#define OFF_WQKV  4554752u    // [1536][512] bf16 = 1572864
#define OFF_WO    6127616u    // [512][512] bf16 = 524288
#define OFF_X0B   6651904u    // [8192][512] bf16 = 8388608
#define OFF_QB    15040512u   // q+k+v bf16 = 25165824
#define OFF_PRE   15040512u   // alias QB[0:8MB]  (QB dead after attnk)
#define OFF_XL    23429120u   // alias QB[8:16MB] [1024][8][512] bf16
#define OFF_ATT   40206336u   // [8192][512] bf16 = 8388608
#define OFF_HS    48594944u   // [2][1024][8][512] u16 = 16777216

extern "C" void kernel_launch(void* const* d_in, const int* in_sizes, int n_in,
                              void* d_out, int out_size, void* d_ws, size_t ws_size,
                              hipStream_t stream) {
  const float* temporal = (const float*)d_in[0];
  const float* w_in = (const float*)d_in[1];  const float* b_in = (const float*)d_in[2];
  const float* wq = (const float*)d_in[3];    const float* bq = (const float*)d_in[4];
  const float* wk = (const float*)d_in[5];    const float* bk = (const float*)d_in[6];
  const float* wv = (const float*)d_in[7];    const float* bv = (const float*)d_in[8];
  const float* wo = (const float*)d_in[9];    const float* bo = (const float*)d_in[10];
  const float* g1 = (const float*)d_in[11];   const float* b1 = (const float*)d_in[12];
  const float* wih_f = (const float*)d_in[13]; const float* whh_f = (const float*)d_in[14];
  const float* bih_f = (const float*)d_in[15]; const float* bhh_f = (const float*)d_in[16];
  const float* wih_b = (const float*)d_in[17]; const float* whh_b = (const float*)d_in[18];
  const float* bih_b = (const float*)d_in[19]; const float* bhh_b = (const float*)d_in[20];
  const float* g2 = (const float*)d_in[21];   const float* b2 = (const float*)d_in[22];
  const float* w_out = (const float*)d_in[23]; const float* b_out = (const float*)d_in[24];

  char* ws = (char*)d_ws;
  float* EMB = (float*)(ws + OFF_EMB);
  u32* HX   = (u32*)(ws + OFF_HX);
  u16* A0   = (u16*)(ws + OFF_A0);
  u16* WIN  = (u16*)(ws + OFF_WIN);
  u16* WQKV = (u16*)(ws + OFF_WQKV);
  u16* WOb  = (u16*)(ws + OFF_WO);
  u16* X0B  = (u16*)(ws + OFF_X0B);
  u16* QB   = (u16*)(ws + OFF_QB);
  u16* PRE  = (u16*)(ws + OFF_PRE);
  u16* XL   = (u16*)(ws + OFF_XL);
  u16* ATT  = (u16*)(ws + OFF_ATT);
  u16* HS   = (u16*)(ws + OFF_HS);

  (void)hipFuncSetAttribute((const void*)lstmk, hipFuncAttributeMaxDynamicSharedMemorySize, 73728);

  zerok<<<24,256,0,stream>>>((u32*)(ws + OFF_EMB));  // EMB + HX (98304 B)

  cvtk<<<2048,256,0,stream>>>(temporal, A0, 2097152);
  cvtk<<<128, 256,0,stream>>>(w_in, WIN, 131072);
  cvtk<<<256, 256,0,stream>>>(wq, WQKV,           262144);
  cvtk<<<256, 256,0,stream>>>(wk, WQKV + 262144,  262144);
  cvtk<<<256, 256,0,stream>>>(wv, WQKV + 524288,  262144);
  cvtk<<<256, 256,0,stream>>>(wo, WOb, 262144);

  gemm128<0><<<dim3(4,64), 256, 0, stream>>>(A0, WIN, b_in, nullptr, nullptr, nullptr, X0B, 8192, 512, 256);
  gemm128<1><<<dim3(12,64),256, 0, stream>>>(X0B, WQKV, bq, bk, bv, nullptr, QB, 8192, 1536, 512);
  attnk<<<1024,256,0,stream>>>(QB, QB + 4194304, QB + 8388608, ATT);
  gemm128<3><<<dim3(4,64), 256, 0, stream>>>(ATT, WOb, bo, nullptr, nullptr, X0B, PRE, 8192, 512, 512);
  ln1k<<<2048,256,0,stream>>>(PRE, g1, b1, XL);
  lstmk<<<32,512,73728,stream>>>(XL, wih_f, whh_f, bih_f, bhh_f, wih_b, whh_b, bih_b, bhh_b, HX, HS);
  ln2k<<<128,256,0,stream>>>(HS, g2, b2, EMB);
  fink<<<16,256,0,stream>>>(EMB, w_out, b_out, (float*)d_out);
}

// Round 13
// 3389.799 us; speedup vs baseline: 1.2624x; 1.2624x over previous
//
#include <hip/hip_runtime.h>

typedef unsigned short u16;
typedef unsigned int   u32;
typedef unsigned long long u64;
typedef __attribute__((ext_vector_type(8))) short short8v;
typedef __attribute__((ext_vector_type(4))) float f32x4;
typedef __attribute__((ext_vector_type(4))) unsigned int u32x4;

#define DINL __device__ __forceinline__

DINL u16 f2bf(float f){ union{float f;u32 u;} v{f}; return (u16)((v.u + 0x7fffu + ((v.u>>16)&1u))>>16); }
DINL float bf2f(u16 b){ union{u32 u;float f;} v{(u32)b<<16}; return v.f; }
DINL f32x4 MFMA16(short8v a, short8v b, f32x4 c){ return __builtin_amdgcn_mfma_f32_16x16x32_bf16(a,b,c,0,0,0); }
DINL void gl16(const void* g, void* l){
  __builtin_amdgcn_global_load_lds((const __attribute__((address_space(1))) void*)g,
                                   (__attribute__((address_space(3))) void*)l, 16, 0, 0);
}
DINL float wredd(float v){
#pragma unroll
  for (int m=1;m<64;m<<=1) v += __shfl_xor(v, m);
  return v;
}
DINL float sigm(float x){ return 1.f/(1.f+__expf(-x)); }
DINL float tanh_(float x){ return 2.f/(1.f+__expf(-2.f*x)) - 1.f; }

// ---------------- zero fill (16B per thread, exact grid) ----------------
__global__ __launch_bounds__(256) void zerok(u32* __restrict__ dst){
  size_t i = ((size_t)blockIdx.x*256 + threadIdx.x)*4;
  u32x4 z = {0,0,0,0};
  *(u32x4*)(dst + i) = z;
}

// ---------------- generic fp32 -> bf16 convert ----------------
__global__ __launch_bounds__(256) void cvtk(const float* __restrict__ src, u16* __restrict__ dst, int n){
  int i = (blockIdx.x*256 + threadIdx.x)*4;
  float4 v = *(const float4*)(src + i);
  dst[i+0]=f2bf(v.x); dst[i+1]=f2bf(v.y); dst[i+2]=f2bf(v.z); dst[i+3]=f2bf(v.w);
}

// ---------------- fused weight convert (w_in | wq | wk | wv | wo) ----------------
__global__ __launch_bounds__(256) void cvtw(const float* __restrict__ w_in, const float* __restrict__ wq,
                                            const float* __restrict__ wk,  const float* __restrict__ wv,
                                            const float* __restrict__ wo,
                                            u16* __restrict__ WIN, u16* __restrict__ WQKV, u16* __restrict__ WOb){
  int b = blockIdx.x;
  const float* src; u16* dst; int idx;
  if (b < 128)      { src = w_in; dst = WIN;            idx = b; }
  else if (b < 384) { src = wq;   dst = WQKV;           idx = b - 128; }
  else if (b < 640) { src = wk;   dst = WQKV + 262144;  idx = b - 384; }
  else if (b < 896) { src = wv;   dst = WQKV + 524288;  idx = b - 640; }
  else              { src = wo;   dst = WOb;            idx = b - 896; }
  int i = (idx*256 + threadIdx.x)*4;
  float4 v = *(const float4*)(src + i);
  dst[i+0]=f2bf(v.x); dst[i+1]=f2bf(v.y); dst[i+2]=f2bf(v.z); dst[i+3]=f2bf(v.w);
}

// ---------------- 128x128 bf16 MFMA GEMM, m97 structure ----------------
template<int EPI>
__global__ __launch_bounds__(256) void gemm128(
    const u16* __restrict__ A, const u16* __restrict__ W,
    const float* __restrict__ bias0, const float* __restrict__ bias1, const float* __restrict__ bias2,
    const u16* __restrict__ resid, u16* __restrict__ out, int M, int N, int K)
{
  __shared__ __align__(16) u16 Al[128*64];
  __shared__ __align__(16) u16 Bl[128*64];
  const int tid = threadIdx.x, lane = tid & 63, w = tid >> 6;
  const int wr = w >> 1, wc = w & 1;
  const int m0 = blockIdx.y * 128, n0 = blockIdx.x * 128;
  f32x4 acc[4][4] = {};
  for (int k0 = 0; k0 < K; k0 += 64) {
#pragma unroll
    for (int j = 0; j < 4; ++j) {
      int idx = (j*4 + w)*64 + lane;
      int r = idx >> 3, c8 = idx & 7;
      gl16(A + (size_t)(m0 + r)*K + k0 + c8*8, (void*)(Al + (size_t)(j*4+w)*512));
      gl16(W + (size_t)(n0 + r)*K + k0 + c8*8, (void*)(Bl + (size_t)(j*4+w)*512));
    }
    __syncthreads();
#pragma unroll
    for (int kk = 0; kk < 2; ++kk) {
      short8v af[4], bf[4];
#pragma unroll
      for (int i = 0; i < 4; ++i)
        af[i] = *(const short8v*)(Al + ((wr*64 + i*16 + (lane&15))*64 + kk*32 + (lane>>4)*8));
#pragma unroll
      for (int i = 0; i < 4; ++i)
        bf[i] = *(const short8v*)(Bl + ((wc*64 + i*16 + (lane&15))*64 + kk*32 + (lane>>4)*8));
#pragma unroll
      for (int mi=0;mi<4;++mi)
#pragma unroll
        for (int ni=0;ni<4;++ni)
          acc[mi][ni] = MFMA16(af[mi], bf[ni], acc[mi][ni]);
    }
    __syncthreads();
  }
#pragma unroll
  for (int mi=0;mi<4;++mi)
#pragma unroll
    for (int ni=0;ni<4;++ni)
#pragma unroll
      for (int r=0;r<4;++r) {
        int m = m0 + wr*64 + mi*16 + (lane>>4)*4 + r;
        int n = n0 + wc*64 + ni*16 + (lane&15);
        float v = acc[mi][ni][r];
        if constexpr (EPI == 0) {
          int t = m & 1023;
          float ang = (float)t * expf((float)(n & ~1) * (-9.210340371976184f/512.f));
          v += bias0[n] + ((n & 1) ? cosf(ang) : sinf(ang));
          out[(size_t)m*512 + n] = f2bf(v);
        } else if constexpr (EPI == 1) {
          int g = n >> 9, n5 = n & 511, hh = n5 >> 6, dh = n5 & 63;
          v += (g==0 ? bias0 : g==1 ? bias1 : bias2)[n5];
          size_t bh = (size_t)((m>>10)*8 + hh);
          u16 val = f2bf(v);
          if (g == 0)      out[(bh*1024 + (m&1023))*64 + dh] = val;
          else if (g == 1) out[4194304 + (bh*1024 + (m&1023))*64 + dh] = val;
          else             out[8388608 + (bh*64 + dh)*1024 + (m&1023)] = val;
        } else {
          v += bias0[n] + bf2f(resid[(size_t)m*512 + n]);
          out[(size_t)m*512 + n] = f2bf(v);
        }
      }
}

// ---------------- causal flash attention ----------------
__global__ __launch_bounds__(256) void attnk(const u16* __restrict__ qb, const u16* __restrict__ kb,
                                             const u16* __restrict__ vt, u16* __restrict__ attno)
{
  __shared__ __align__(16) u16 P[4][16][72];
  const int tid = threadIdx.x, lane = tid & 63, w = tid >> 6;
  const int bh = blockIdx.x >> 4, qblk = blockIdx.x & 15;
  const int b = bh >> 3, h = bh & 7;
  const float scale = 0.125f;
  short8v qf[2];
  {
    const u16* qbase = qb + ((size_t)bh*1024 + qblk*64 + w*16)*64;
#pragma unroll
    for (int kk=0;kk<2;++kk)
      qf[kk] = *(const short8v*)(qbase + (size_t)(lane&15)*64 + kk*32 + (lane>>4)*8);
  }
  f32x4 o[4] = {};
  float mrun[4], lrun[4];
#pragma unroll
  for (int r=0;r<4;++r){ mrun[r] = -1e30f; lrun[r] = 0.f; }
  for (int kblk = 0; kblk <= qblk; ++kblk) {
    f32x4 s[4] = {};
#pragma unroll
    for (int kk=0;kk<2;++kk)
#pragma unroll
      for (int nt=0;nt<4;++nt) {
        short8v kf = *(const short8v*)(kb + ((size_t)bh*1024 + kblk*64 + nt*16 + (lane&15))*64 + kk*32 + (lane>>4)*8);
        s[nt] = MFMA16(qf[kk], kf, s[nt]);
      }
    float pnew[4][4];
#pragma unroll
    for (int r=0;r<4;++r) {
      int q = qblk*64 + w*16 + (lane>>4)*4 + r;
      float sv[4]; float rowmax = -1e30f;
#pragma unroll
      for (int nt=0;nt<4;++nt) {
        int key = kblk*64 + nt*16 + (lane&15);
        float x = s[nt][r]*scale;
        if (key > q) x = -1e30f;
        sv[nt] = x; rowmax = fmaxf(rowmax, x);
      }
#pragma unroll
      for (int msk=1; msk<16; msk<<=1) rowmax = fmaxf(rowmax, __shfl_xor(rowmax, msk));
      float mnew = fmaxf(mrun[r], rowmax);
      float sf = __expf(mrun[r]-mnew);
      float psum = 0.f;
#pragma unroll
      for (int nt=0;nt<4;++nt){ float p = __expf(sv[nt]-mnew); pnew[nt][r]=p; psum += p; }
#pragma unroll
      for (int msk=1; msk<16; msk<<=1) psum += __shfl_xor(psum, msk);
      lrun[r] = lrun[r]*sf + psum;
      mrun[r] = mnew;
#pragma unroll
      for (int nt=0;nt<4;++nt) o[nt][r] *= sf;
    }
#pragma unroll
    for (int nt=0;nt<4;++nt)
#pragma unroll
      for (int r=0;r<4;++r)
        P[w][(lane>>4)*4+r][nt*16+(lane&15)] = f2bf(pnew[nt][r]);
#pragma unroll
    for (int kk=0;kk<2;++kk) {
      short8v pf = *(const short8v*)&P[w][lane&15][kk*32 + (lane>>4)*8];
#pragma unroll
      for (int nt=0;nt<4;++nt) {
        short8v vf = *(const short8v*)(vt + ((size_t)bh*64 + nt*16 + (lane&15))*1024 + kblk*64 + kk*32 + (lane>>4)*8);
        o[nt] = MFMA16(pf, vf, o[nt]);
      }
    }
  }
#pragma unroll
  for (int nt=0;nt<4;++nt)
#pragma unroll
    for (int r=0;r<4;++r) {
      int q = qblk*64 + w*16 + (lane>>4)*4 + r;
      int dh = nt*16 + (lane&15);
      attno[((size_t)b*1024 + q)*512 + h*64 + dh] = f2bf(o[nt][r] / lrun[r]);
    }
}

// ---------------- LayerNorm 1 (rows of 512), write x_lstm [t][b][512] bf16 ----------------
__global__ __launch_bounds__(256) void ln1k(const u16* __restrict__ pre, const float* __restrict__ g1,
                                            const float* __restrict__ b1, u16* __restrict__ xl){
  int row = blockIdx.x*4 + (threadIdx.x>>6), lane = threadIdx.x&63;
  short8v xv = *(const short8v*)(pre + (size_t)row*512 + lane*8);
  float v[8], s=0.f, s2=0.f;
#pragma unroll
  for (int e=0;e<8;++e){ v[e]=bf2f((u16)xv[e]); s+=v[e]; s2+=v[e]*v[e]; }
  s = wredd(s); s2 = wredd(s2);
  float mu = s*(1.f/512.f);
  float rs = rsqrtf(s2*(1.f/512.f) - mu*mu + 1e-5f);
  int b = row>>10, t = row&1023;
  short8v ov;
#pragma unroll
  for (int e=0;e<8;++e){ int c=lane*8+e; ov[e]=(short)f2bf((v[e]-mu)*rs*g1[c]+b1[c]); }
  *(short8v*)(xl + ((size_t)t*8 + b)*512 + lane*8) = ov;
}

// ---------------- persistent bidirectional LSTM — R6-exact (best measured: 3105 us) ----------------
// 32 WGs x 512 thr: d = blk>>4, slice = blk&15 owns 32 units. Wave w owns K-eighth.
// Weights as MFMA B-fragments in VGPRs. Exchange: tagged u32 hot window (parity p=t&1),
// producer sc0 sc1 write-through; consumer batched 4x global_load_dwordx4 sc0 sc1 + ONE
// vmcnt(0) per retry. Reduce: [2][8w][8nt][32][4] f32x4 (4-way b128 alias = 1.58x, cheap).
__global__ __launch_bounds__(512, 2) void lstmk(
    const u16* __restrict__ xl,
    const float* __restrict__ wih_f, const float* __restrict__ whh_f,
    const float* __restrict__ bih_f, const float* __restrict__ bhh_f,
    const float* __restrict__ wih_b, const float* __restrict__ whh_b,
    const float* __restrict__ bih_b, const float* __restrict__ bhh_b,
    u32* __restrict__ hx, u16* __restrict__ hs)
{
  extern __shared__ float RED[];        // [2][8 w][8 nt][32 lane][4 reg] = 64 KB

  const int tid = threadIdx.x, lane = tid&63, w = tid>>6;
  const int d = blockIdx.x >> 4, slice = blockIdx.x & 15, u0 = slice*32;
  const float* WIHg = d ? wih_b : wih_f;
  const float* WHHg = d ? whh_b : whh_f;
  const float* BIH  = d ? bih_b : bih_f;
  const float* BHH  = d ? bhh_b : bhh_f;

  const int l15 = lane&15, l16 = lane>>4;

  // ---- load weight fragments into registers: frag[nt][kk], nt = g*2+uh ----
  short8v wi[8][2], wh[8][2];
#pragma unroll
  for (int nt=0; nt<8; ++nt) {
    const int g = nt>>1, uh = nt&1;
    const size_t row = (size_t)(g*512 + u0 + uh*16 + l15);
#pragma unroll
    for (int kk=0; kk<2; ++kk) {
      const int k = w*64 + kk*32 + l16*8;
      const float* pi = WIHg + row*512 + k;
      const float* ph = WHHg + row*512 + k;
      float4 a0 = *(const float4*)pi, a1 = *(const float4*)(pi+4);
      float4 b0 = *(const float4*)ph, b1 = *(const float4*)(ph+4);
      short8v si, sh;
      si[0]=(short)f2bf(a0.x); si[1]=(short)f2bf(a0.y); si[2]=(short)f2bf(a0.z); si[3]=(short)f2bf(a0.w);
      si[4]=(short)f2bf(a1.x); si[5]=(short)f2bf(a1.y); si[6]=(short)f2bf(a1.z); si[7]=(short)f2bf(a1.w);
      sh[0]=(short)f2bf(b0.x); sh[1]=(short)f2bf(b0.y); sh[2]=(short)f2bf(b0.z); sh[3]=(short)f2bf(b0.w);
      sh[4]=(short)f2bf(b1.x); sh[5]=(short)f2bf(b1.y); sh[6]=(short)f2bf(b1.z); sh[7]=(short)f2bf(b1.w);
      wi[nt][kk] = si; wh[nt][kk] = sh;
    }
  }

  const bool act = tid < 256;
  const int b_ = tid>>5, u_ = tid&31;           // valid when act
  float c_state = 0.f, bias_c[4];
  if (act)
#pragma unroll
    for (int g=0;g<4;++g) bias_c[g] = BIH[g*512+u0+u_] + BHH[g*512+u0+u_];

  __syncthreads();

  for (int t = 0; t < 1024; ++t) {
    const int te = d ? 1023 - t : t;
    f32x4 acc[8] = {};
    { // x @ wih^T — h-independent
      const u16* xb = xl + ((size_t)te*8 + (lane&7))*512 + w*64 + l16*8;
      short8v xf0 = *(const short8v*)(xb);
      short8v xf1 = *(const short8v*)(xb + 32);
#pragma unroll
      for (int nt=0; nt<8; ++nt) acc[nt] = MFMA16(xf0, wi[nt][0], acc[nt]);
#pragma unroll
      for (int nt=0; nt<8; ++nt) acc[nt] = MFMA16(xf1, wi[nt][1], acc[nt]);
    }
    if (t > 0) {
      const u32 tg = (u32)t;
      // hot window parity (t-1)&1; this wave's K-eighth fragment
      const u32* pb = hx + ((size_t)d*2 + ((t-1)&1))*4096 + (size_t)(lane&7)*512 + w*64 + l16*8;
      u32x4 q0,q1,q2,q3;
      for (;;) {
        asm volatile(
          "global_load_dwordx4 %0, %4, off sc0 sc1\n\t"
          "global_load_dwordx4 %1, %4, off offset:16 sc0 sc1\n\t"
          "global_load_dwordx4 %2, %4, off offset:128 sc0 sc1\n\t"
          "global_load_dwordx4 %3, %4, off offset:144 sc0 sc1\n\t"
          "s_waitcnt vmcnt(0)"
          : "=&v"(q0),"=&v"(q1),"=&v"(q2),"=&v"(q3)
          : "v"(pb));
        bool ok = true;
#pragma unroll
        for (int e=0;e<4;++e) {
          ok = ok && ((q0[e]&0xffffu)==tg) && ((q1[e]&0xffffu)==tg)
                  && ((q2[e]&0xffffu)==tg) && ((q3[e]&0xffffu)==tg);
        }
        if (__all(ok)) break;
        __builtin_amdgcn_s_sleep(1);
      }
      short8v hf0, hf1;
#pragma unroll
      for (int e=0;e<4;++e) {
        hf0[e]   = (short)(q0[e] >> 16);
        hf0[4+e] = (short)(q1[e] >> 16);
        hf1[e]   = (short)(q2[e] >> 16);
        hf1[4+e] = (short)(q3[e] >> 16);
      }
#pragma unroll
      for (int nt=0; nt<8; ++nt) acc[nt] = MFMA16(hf0, wh[nt][0], acc[nt]);
#pragma unroll
      for (int nt=0; nt<8; ++nt) acc[nt] = MFMA16(hf1, wh[nt][1], acc[nt]);
    }
    float* R = RED + (size_t)(t & 1)*8192;
    if (lane < 32)
#pragma unroll
      for (int nt=0; nt<8; ++nt)
        *(f32x4*)(R + ((size_t)(w*8+nt)*32 + lane)*4) = acc[nt];
    __syncthreads();
    if (act) {
      const int lc = (u_&15) + 16*(b_>>2), rg = b_&3, uh = u_>>4;
      float gates[4];
#pragma unroll
      for (int g=0;g<4;++g) {
        float s = 0.f;
#pragma unroll
        for (int wv=0; wv<8; ++wv) s += R[((size_t)(wv*8 + g*2 + uh)*32 + lc)*4 + rg];
        gates[g] = s + bias_c[g];
      }
      float ig = sigm(gates[0]), fg = sigm(gates[1]), gg = tanh_(gates[2]), og = sigm(gates[3]);
      c_state = fg*c_state + ig*gg;
      u16 hv = f2bf(og * tanh_(c_state));
      hs[((size_t)(d*1024 + te)*8 + b_)*512 + u0 + u_] = hv;          // history (cached)
      u32 word = ((u32)hv << 16) | (u32)(t + 1);
      u32* dst = hx + ((size_t)d*2 + (t&1))*4096 + (size_t)b_*512 + u0 + u_;
      asm volatile("global_store_dword %0, %1, off sc0 sc1" :: "v"(dst), "v"(word) : "memory");
    }
    // no trailing barrier: RED double-buffered by t&1; readiness carried by tags
  }
}

// ---------------- LayerNorm 2 + time-mean accumulate ----------------
__global__ __launch_bounds__(256) void ln2k(const u16* __restrict__ hs, const float* __restrict__ g2,
                                            const float* __restrict__ b2, float* __restrict__ emb){
  __shared__ float accl[4][1024];
  int b = blockIdx.x>>4, chunk = blockIdx.x&15;
  int lane = threadIdx.x&63, w = threadIdx.x>>6;
  for (int i=lane;i<1024;i+=64) accl[w][i]=0.f;
#pragma unroll 1
  for (int i=0;i<16;++i) {
    int t = chunk*64 + w*16 + i;
    short8v xf = *(const short8v*)(hs + ((size_t)t*8 + b)*512 + lane*8);
    short8v xb = *(const short8v*)(hs + ((size_t)(1024+t)*8 + b)*512 + lane*8);
    float vf[8], vb[8], s=0.f, s2=0.f;
#pragma unroll
    for (int e=0;e<8;++e){ vf[e]=bf2f((u16)xf[e]); vb[e]=bf2f((u16)xb[e]);
                           s += vf[e]+vb[e]; s2 += vf[e]*vf[e]+vb[e]*vb[e]; }
    s = wredd(s); s2 = wredd(s2);
    float mu = s*(1.f/1024.f);
    float rs = rsqrtf(s2*(1.f/1024.f) - mu*mu + 1e-5f);
#pragma unroll
    for (int e=0;e<8;++e){
      int c = lane*8+e;
      accl[w][c]     += (vf[e]-mu)*rs*g2[c]     + b2[c];
      accl[w][512+c] += (vb[e]-mu)*rs*g2[512+c] + b2[512+c];
    }
  }
  __syncthreads();
  for (int c = threadIdx.x; c < 1024; c += 256)
    atomicAdd(emb + (size_t)b*1024 + c, accl[0][c]+accl[1][c]+accl[2][c]+accl[3][c]);
}

// ---------------- final projection ----------------
__global__ __launch_bounds__(256) void fink(const float* __restrict__ emb, const float* __restrict__ w_out,
                                            const float* __restrict__ b_out, float* __restrict__ out){
  int gid = blockIdx.x*256 + threadIdx.x;
  int n = gid>>3, b = gid&7;
  const float* e = emb + (size_t)b*1024;
  const float* wr = w_out + (size_t)n*1024;
  float s = 0.f;
  for (int k=0;k<1024;k+=4) {
    float4 ev = *(const float4*)(e+k);
    float4 wv = *(const float4*)(wr+k);
    s += ev.x*wv.x + ev.y*wv.y + ev.z*wv.z + ev.w*wv.w;
  }
  out[(size_t)b*512 + n] = b_out[n] + s*(1.f/1024.f);
}

// ---------------- workspace layout (bytes) ----------------
#define OFF_EMB   0u          // [8][1024] f32 = 32768           (zeroed each launch)
#define OFF_HX    32768u      // [2][2][8][512] u32 = 65536      (zeroed each launch)
#define OFF_A0    98304u      // [8192][256] bf16 = 4194304
#define OFF_WIN   4292608u    // [512][256] bf16 = 262144
#define OFF_WQKV  4554752u    // [1536][512] bf16 = 1572864
#define OFF_WO    6127616u    // [512][512] bf16 = 524288
#define OFF_X0B   6651904u    // [8192][512] bf16 = 8388608
#define OFF_QB    15040512u   // q+k+v bf16 = 25165824
#define OFF_PRE   15040512u   // alias QB[0:8MB]  (QB dead after attnk)
#define OFF_XL    23429120u   // alias QB[8:16MB] [1024][8][512] bf16
#define OFF_ATT   40206336u   // [8192][512] bf16 = 8388608
#define OFF_HS    48594944u   // [2][1024][8][512] u16 = 16777216

extern "C" void kernel_launch(void* const* d_in, const int* in_sizes, int n_in,
                              void* d_out, int out_size, void* d_ws, size_t ws_size,
                              hipStream_t stream) {
  const float* temporal = (const float*)d_in[0];
  const float* w_in = (const float*)d_in[1];  const float* b_in = (const float*)d_in[2];
  const float* wq = (const float*)d_in[3];    const float* bq = (const float*)d_in[4];
  const float* wk = (const float*)d_in[5];    const float* bk = (const float*)d_in[6];
  const float* wv = (const float*)d_in[7];    const float* bv = (const float*)d_in[8];
  const float* wo = (const float*)d_in[9];    const float* bo = (const float*)d_in[10];
  const float* g1 = (const float*)d_in[11];   const float* b1 = (const float*)d_in[12];
  const float* wih_f = (const float*)d_in[13]; const float* whh_f = (const float*)d_in[14];
  const float* bih_f = (const float*)d_in[15]; const float* bhh_f = (const float*)d_in[16];
  const float* wih_b = (const float*)d_in[17]; const float* whh_b = (const float*)d_in[18];
  const float* bih_b = (const float*)d_in[19]; const float* bhh_b = (const float*)d_in[20];
  const float* g2 = (const float*)d_in[21];   const float* b2 = (const float*)d_in[22];
  const float* w_out = (const float*)d_in[23]; const float* b_out = (const float*)d_in[24];

  char* ws = (char*)d_ws;
  float* EMB = (float*)(ws + OFF_EMB);
  u32* HX   = (u32*)(ws + OFF_HX);
  u16* A0   = (u16*)(ws + OFF_A0);
  u16* WIN  = (u16*)(ws + OFF_WIN);
  u16* WQKV = (u16*)(ws + OFF_WQKV);
  u16* WOb  = (u16*)(ws + OFF_WO);
  u16* X0B  = (u16*)(ws + OFF_X0B);
  u16* QB   = (u16*)(ws + OFF_QB);
  u16* PRE  = (u16*)(ws + OFF_PRE);
  u16* XL   = (u16*)(ws + OFF_XL);
  u16* ATT  = (u16*)(ws + OFF_ATT);
  u16* HS   = (u16*)(ws + OFF_HS);

  (void)hipFuncSetAttribute((const void*)lstmk, hipFuncAttributeMaxDynamicSharedMemorySize, 65536);

  zerok<<<24,256,0,stream>>>((u32*)(ws + OFF_EMB));  // EMB + HX (98304 B)

  cvtk<<<2048,256,0,stream>>>(temporal, A0, 2097152);
  cvtw<<<1152,256,0,stream>>>(w_in, wq, wk, wv, wo, WIN, WQKV, WOb);

  gemm128<0><<<dim3(4,64), 256, 0, stream>>>(A0, WIN, b_in, nullptr, nullptr, nullptr, X0B, 8192, 512, 256);
  gemm128<1><<<dim3(12,64),256, 0, stream>>>(X0B, WQKV, bq, bk, bv, nullptr, QB, 8192, 1536, 512);
  attnk<<<1024,256,0,stream>>>(QB, QB + 4194304, QB + 8388608, ATT);
  gemm128<3><<<dim3(4,64), 256, 0, stream>>>(ATT, WOb, bo, nullptr, nullptr, X0B, PRE, 8192, 512, 512);
  ln1k<<<2048,256,0,stream>>>(PRE, g1, b1, XL);
  lstmk<<<32,512,65536,stream>>>(XL, wih_f, whh_f, bih_f, bhh_f, wih_b, whh_b, bih_b, bhh_b, HX, HS);
  ln2k<<<128,256,0,stream>>>(HS, g2, b2, EMB);
  fink<<<16,256,0,stream>>>(EMB, w_out, b_out, (float*)d_out);
}